// Round 2
// baseline (304.572 us; speedup 1.0000x reference)
//
#include <hip/hip_runtime.h>
#include <hip/hip_bf16.h>
#include <stdint.h>

#define E     1024
#define NSEQ  2048
#define NH    16
#define HD    64
#define KSEL  12
#define MROWS 4096   // B*N

typedef unsigned short u16;
typedef __attribute__((ext_vector_type(8))) short bf16x8;
typedef __attribute__((ext_vector_type(4))) float f32x4;
typedef __attribute__((ext_vector_type(4))) unsigned short u16x4;

__device__ __forceinline__ float b2f(u16 u) {
  return __builtin_bit_cast(float, (unsigned)u << 16);
}
__device__ __forceinline__ u16 f2b(float f) {
  return __builtin_bit_cast(u16, __float2bfloat16(f));
}

__device__ __forceinline__ void gload_lds16(const void* g, void* l) {
  auto gp = reinterpret_cast<__attribute__((address_space(1))) unsigned int*>(
      reinterpret_cast<uintptr_t>(g));
  auto lp = reinterpret_cast<__attribute__((address_space(3))) unsigned int*>(
      reinterpret_cast<uintptr_t>(l));
  __builtin_amdgcn_global_load_lds(gp, lp, 16, 0, 0);
}

// ---------------- dtype detector: flag=1 if bf16, 0 if fp32 -------------------
// bf16 N(0,1): exponent field of nearly all u16s lies in [100,140] (~1024/1024).
// fp32 N(0,1): low u16 of each word has ~uniform exponent field (~594/1024).
__global__ void detect_k(const u16* __restrict__ x, int* __restrict__ flag) {
  int cnt = 0;
  for (int i = threadIdx.x; i < 1024; i += 64) {
    const unsigned e = (x[i] >> 7) & 0xFF;
    cnt += (e >= 100 && e <= 140) ? 1 : 0;
  }
#pragma unroll
  for (int off = 1; off < 64; off <<= 1) cnt += __shfl_xor(cnt, off, 64);
  if (threadIdx.x == 0) flag[0] = (cnt > 900) ? 1 : 0;
}

// ---------------- x -> bf16 copy (convert if fp32) ----------------------------
__global__ void xconv_k(const void* __restrict__ xin, u16* __restrict__ xc,
                        const int* __restrict__ flag) {
  const int f = flag[0];
  const int stride = gridDim.x * blockDim.x;
  if (f) {
    const u16* s = (const u16*)xin;
    for (int i = blockIdx.x * blockDim.x + threadIdx.x; i < MROWS * E; i += stride)
      xc[i] = s[i];
  } else {
    const float* s = (const float*)xin;
    for (int i = blockIdx.x * blockDim.x + threadIdx.x; i < MROWS * E; i += stride)
      xc[i] = f2b(s[i]);
  }
}

// ---------------- weight transpose: Wt[n][k] = bf16(W[k][n]), 4 weights -------
__global__ void transpose4(const void* __restrict__ w0, const void* __restrict__ w1,
                           const void* __restrict__ w2, const void* __restrict__ w3,
                           u16* __restrict__ Wt, const int* __restrict__ flag) {
  __shared__ u16 tile[32][33];
  const void* W = blockIdx.z == 0 ? w0 : blockIdx.z == 1 ? w1 : blockIdx.z == 2 ? w2 : w3;
  const int f = flag[0];
  u16* O = Wt + (size_t)blockIdx.z * (E * E);
  const int tx = threadIdx.x & 31, ty = threadIdx.x >> 5;
  const int bk = blockIdx.y * 32, bn = blockIdx.x * 32;
  if (f) {
    const u16* Wu = (const u16*)W;
    for (int r = ty; r < 32; r += 8)
      tile[r][tx] = Wu[(size_t)(bk + r) * E + bn + tx];
  } else {
    const float* Wf = (const float*)W;
    for (int r = ty; r < 32; r += 8)
      tile[r][tx] = f2b(Wf[(size_t)(bk + r) * E + bn + tx]);
  }
  __syncthreads();
  for (int r = ty; r < 32; r += 8)
    O[(size_t)(bn + r) * E + bk + tx] = tile[tx][r];
}

// ---------------- xp = per-block mean of x (fp32, original precision) ---------
__global__ void xpmean_k(const void* __restrict__ xin, float* __restrict__ xp,
                         const int* __restrict__ flag) {
  const int blk = blockIdx.x;              // rows blk*32 .. +31
  const int f = flag[0];
  const size_t base = (size_t)blk * 32 * E;
  if (f) {
    const u16* x = (const u16*)xin;
    for (int c = threadIdx.x; c < E; c += 256) {
      float s = 0.f;
      for (int r = 0; r < 32; ++r) s += b2f(x[base + (size_t)r * E + c]);
      xp[(size_t)blk * E + c] = s * (1.0f / 32.0f);
    }
  } else {
    const float* x = (const float*)xin;
    for (int c = threadIdx.x; c < E; c += 256) {
      float s = 0.f;
      for (int r = 0; r < 32; ++r) s += x[base + (size_t)r * E + c];
      xp[(size_t)blk * E + c] = s * (1.0f / 32.0f);
    }
  }
}

// ---------------- Qp = xp @ Wq, Kp = xp @ Wk (fp32, original weights) ---------
__global__ void qpkp_k(const float* __restrict__ xp, const void* __restrict__ Wq,
                       const void* __restrict__ Wk, float* __restrict__ Qp,
                       float* __restrict__ Kp, const int* __restrict__ flag) {
  const int row = blockIdx.x;
  const void* W = blockIdx.y ? Wk : Wq;
  float* Out = blockIdx.y ? Kp : Qp;
  const int f = flag[0];
  __shared__ float xr[E];
  for (int e = threadIdx.x; e < E; e += 256) xr[e] = xp[(size_t)row * E + e];
  __syncthreads();
  const int tid = threadIdx.x;
  float a0 = 0.f, a1 = 0.f, a2 = 0.f, a3 = 0.f;
  if (f) {
    const u16* Wu = (const u16*)W;
    for (int k = 0; k < E; ++k) {
      const float xv = xr[k];
      const u16* wr = Wu + (size_t)k * E + tid;
      a0 += xv * b2f(wr[0]);
      a1 += xv * b2f(wr[256]);
      a2 += xv * b2f(wr[512]);
      a3 += xv * b2f(wr[768]);
    }
  } else {
    const float* Wf = (const float*)W;
    for (int k = 0; k < E; ++k) {
      const float xv = xr[k];
      const float* wr = Wf + (size_t)k * E + tid;
      a0 += xv * wr[0];
      a1 += xv * wr[256];
      a2 += xv * wr[512];
      a3 += xv * wr[768];
    }
  }
  Out[(size_t)row * E + tid] = a0;
  Out[(size_t)row * E + tid + 256] = a1;
  Out[(size_t)row * E + tid + 512] = a2;
  Out[(size_t)row * E + tid + 768] = a3;
}

// ---------------- avg_sc[i][j] = (1/32) sum_b Qp[b,i,:].Kp[b,j,:] -------------
__global__ void avgsc_k(const float* __restrict__ Qp, const float* __restrict__ Kp,
                        float* __restrict__ sc) {
  const int i = blockIdx.x, j = threadIdx.x;   // 64 threads
  __shared__ float qrow[2][E];
  for (int e = j; e < 2 * E; e += 64)
    qrow[e >> 10][e & 1023] = Qp[(size_t)((e >> 10) * 64 + i) * E + (e & 1023)];
  __syncthreads();
  float acc = 0.f;
  for (int b = 0; b < 2; ++b) {
    const float* kr = Kp + (size_t)(b * 64 + j) * E;
    const float* qr = qrow[b];
    for (int e = 0; e < E; e += 4)
      acc += qr[e] * kr[e] + qr[e + 1] * kr[e + 1] + qr[e + 2] * kr[e + 2] + qr[e + 3] * kr[e + 3];
  }
  sc[i * 64 + j] = acc * (1.0f / 32.0f);
}

// ---------------- top-12 per row of 64x64 score matrix ------------------------
__global__ void topk_k(const float* __restrict__ sc, int* __restrict__ idxs) {
  __shared__ float s[64][65];
  const int tid = threadIdx.x;                 // 64 threads
  for (int e = tid; e < 4096; e += 64) s[e >> 6][e & 63] = sc[e];
  __syncthreads();
  for (int j = 0; j < KSEL; ++j) {
    float m = -3.4e38f;
    int mi = 0;
    for (int c = 0; c < 64; ++c) {
      float v = s[tid][c];
      if (v > m) { m = v; mi = c; }
    }
    idxs[tid * KSEL + j] = mi;
    s[tid][mi] = -3.4e38f;
  }
}

// ---------------- 128x128 bf16 GEMM: C = A(M,K) @ Bt(N,K)^T -------------------
// MODE 0: QKV, blockIdx.z picks weight/output; z=0/1 write (b,h,n,d), z=2 writes (b,h,d,n)
// MODE 1: final projection; output dtype branches on flag (bf16 or fp32)
template <int MODE>
__launch_bounds__(256, 2)
__global__ void gemm_bt(const u16* __restrict__ A, const u16* __restrict__ BtBase,
                        void* __restrict__ OutBase, const int* __restrict__ flag) {
  __shared__ __attribute__((aligned(16))) u16 At[128 * 32];
  __shared__ __attribute__((aligned(16))) u16 Bs[128 * 32];
  const int tid = threadIdx.x;
  const int wave = tid >> 6, lane = tid & 63;
  const int q4 = lane >> 4, l16 = lane & 15;
  const int wm = (wave >> 1) * 64, wn = (wave & 1) * 64;
  const int bm = blockIdx.x * 128, bn = blockIdx.y * 128;
  const u16* Bmat = BtBase + (MODE == 0 ? (size_t)blockIdx.z * (E * E) : 0);
  const int srow = lane >> 2;          // 0..15
  const int scol = (lane & 3) * 8;     // 0,8,16,24

  f32x4 acc[4][4] = {};

  for (int k0 = 0; k0 < E; k0 += 32) {
#pragma unroll
    for (int r = 0; r < 2; ++r) {
      const int c = r * 4 + wave;
      const int row = c * 16 + srow;
      gload_lds16(A + (size_t)(bm + row) * E + k0 + scol, &At[c * 512 + lane * 8]);
      gload_lds16(Bmat + (size_t)(bn + row) * E + k0 + scol, &Bs[c * 512 + lane * 8]);
    }
    __syncthreads();
    bf16x8 af[4], bfr[4];
#pragma unroll
    for (int mi = 0; mi < 4; ++mi)
      af[mi] = *(const bf16x8*)&At[(wm + mi * 16 + l16) * 32 + q4 * 8];
#pragma unroll
    for (int ni = 0; ni < 4; ++ni)
      bfr[ni] = *(const bf16x8*)&Bs[(wn + ni * 16 + l16) * 32 + q4 * 8];
#pragma unroll
    for (int mi = 0; mi < 4; ++mi)
#pragma unroll
      for (int ni = 0; ni < 4; ++ni)
        acc[mi][ni] = __builtin_amdgcn_mfma_f32_16x16x32_bf16(af[mi], bfr[ni], acc[mi][ni], 0, 0, 0);
    __syncthreads();
  }

  if (MODE == 1) {
    const int f = flag[0];
    if (f) {
      u16* Out = (u16*)OutBase;
#pragma unroll
      for (int mi = 0; mi < 4; ++mi) {
        const int rg0 = bm + wm + mi * 16 + q4 * 4;
#pragma unroll
        for (int ni = 0; ni < 4; ++ni) {
          const int cg = bn + wn + ni * 16 + l16;
#pragma unroll
          for (int r = 0; r < 4; ++r)
            Out[(size_t)(rg0 + r) * E + cg] = f2b(acc[mi][ni][r]);
        }
      }
    } else {
      float* Out = (float*)OutBase;
#pragma unroll
      for (int mi = 0; mi < 4; ++mi) {
        const int rg0 = bm + wm + mi * 16 + q4 * 4;
#pragma unroll
        for (int ni = 0; ni < 4; ++ni) {
          const int cg = bn + wn + ni * 16 + l16;
#pragma unroll
          for (int r = 0; r < 4; ++r)
            Out[(size_t)(rg0 + r) * E + cg] = acc[mi][ni][r];
        }
      }
    }
  } else {
    const int z = blockIdx.z;
    u16* O = (u16*)OutBase + (size_t)z * 4194304;
    if (z < 2) {
#pragma unroll
      for (int mi = 0; mi < 4; ++mi) {
        const int rg0 = bm + wm + mi * 16 + q4 * 4;
        const int b = rg0 >> 11, n0 = rg0 & 2047;
#pragma unroll
        for (int ni = 0; ni < 4; ++ni) {
          const int cg = bn + wn + ni * 16 + l16;
          const int h = cg >> 6, d = cg & 63;
          u16* dst = O + (size_t)(b * NH + h) * NSEQ * HD + d;
#pragma unroll
          for (int r = 0; r < 4; ++r)
            dst[(size_t)(n0 + r) * HD] = f2b(acc[mi][ni][r]);
        }
      }
    } else {
#pragma unroll
      for (int mi = 0; mi < 4; ++mi) {
        const int rg0 = bm + wm + mi * 16 + q4 * 4;
        const int b = rg0 >> 11, n0 = rg0 & 2047;
#pragma unroll
        for (int ni = 0; ni < 4; ++ni) {
          const int cg = bn + wn + ni * 16 + l16;
          const int h = cg >> 6, d = cg & 63;
          u16x4 v;
          v.x = f2b(acc[mi][ni][0]);
          v.y = f2b(acc[mi][ni][1]);
          v.z = f2b(acc[mi][ni][2]);
          v.w = f2b(acc[mi][ni][3]);
          *(u16x4*)(O + ((size_t)(b * NH + h) * HD + d) * NSEQ + n0) = v;
        }
      }
    }
  }
}

// ---------------- sparse attention: one block per (t,h,b) ---------------------
// Q,K in (b,h,n,d); V in (b,h,d,n). 4 waves; wave w owns selected blocks 3w..3w+2.
__launch_bounds__(256, 2)
__global__ void attn_k(const u16* __restrict__ Q, const u16* __restrict__ K,
                       const u16* __restrict__ Vt, const int* __restrict__ idxs,
                       u16* __restrict__ Oat) {
  const int t = blockIdx.x, h = blockIdx.y, b = blockIdx.z;
  const int tid = threadIdx.x, w = tid >> 6, lane = tid & 63;
  const int q4 = lane >> 4, l16 = lane & 15;
  __shared__ __attribute__((aligned(16))) u16 P[32 * 392];  // padded stride 392
  __shared__ float Ored[4][32][64];
  __shared__ float redm[4][32];
  __shared__ float reds[4][32];
  const size_t hb = (size_t)(b * NH + h) * NSEQ * HD;
  const u16* Qh = Q + hb;
  const u16* Kh = K + hb;
  const u16* Vh = Vt + hb;   // (d, n) layout, same head stride
  int blks[3];
#pragma unroll
  for (int i = 0; i < 3; ++i) blks[i] = idxs[t * KSEL + w * 3 + i];

  // ---- S = Q K^T for this wave's 96 keys ----
  f32x4 accS[2][6] = {};
#pragma unroll
  for (int ks = 0; ks < 2; ++ks) {
    bf16x8 aq[2];
#pragma unroll
    for (int mi = 0; mi < 2; ++mi)
      aq[mi] = *(const bf16x8*)&Qh[(size_t)(t * 32 + mi * 16 + l16) * HD + ks * 32 + q4 * 8];
#pragma unroll
    for (int ni = 0; ni < 6; ++ni) {
      const int n = blks[ni >> 1] * 32 + (ni & 1) * 16 + l16;
      bf16x8 bk = *(const bf16x8*)&Kh[(size_t)n * HD + ks * 32 + q4 * 8];
#pragma unroll
      for (int mi = 0; mi < 2; ++mi)
        accS[mi][ni] = __builtin_amdgcn_mfma_f32_16x16x32_bf16(aq[mi], bk, accS[mi][ni], 0, 0, 0);
    }
  }

  // ---- softmax (rows spread over 16-lane groups; cross-wave via LDS) ----
  float rmax[2][4];
#pragma unroll
  for (int mi = 0; mi < 2; ++mi)
#pragma unroll
    for (int r = 0; r < 4; ++r) {
      float m = accS[mi][0][r];
#pragma unroll
      for (int ni = 1; ni < 6; ++ni) m = fmaxf(m, accS[mi][ni][r]);
      rmax[mi][r] = m;
    }
#pragma unroll
  for (int off = 1; off < 16; off <<= 1)
#pragma unroll
    for (int mi = 0; mi < 2; ++mi)
#pragma unroll
      for (int r = 0; r < 4; ++r)
        rmax[mi][r] = fmaxf(rmax[mi][r], __shfl_xor(rmax[mi][r], off, 64));
  if (l16 == 0) {
#pragma unroll
    for (int mi = 0; mi < 2; ++mi)
#pragma unroll
      for (int r = 0; r < 4; ++r)
        redm[w][mi * 16 + q4 * 4 + r] = rmax[mi][r];
  }
  __syncthreads();
  const float cexp = 0.125f * 1.44269504088896f;  // scale * log2(e)
  float gmax[2][4];
#pragma unroll
  for (int mi = 0; mi < 2; ++mi)
#pragma unroll
    for (int r = 0; r < 4; ++r) {
      const int row = mi * 16 + q4 * 4 + r;
      gmax[mi][r] = fmaxf(fmaxf(redm[0][row], redm[1][row]), fmaxf(redm[2][row], redm[3][row]));
    }
  float rsum[2][4] = {};
#pragma unroll
  for (int mi = 0; mi < 2; ++mi)
#pragma unroll
    for (int ni = 0; ni < 6; ++ni)
#pragma unroll
      for (int r = 0; r < 4; ++r) {
        const float e = __builtin_exp2f((accS[mi][ni][r] - gmax[mi][r]) * cexp);
        accS[mi][ni][r] = e;
        rsum[mi][r] += e;
      }
#pragma unroll
  for (int off = 1; off < 16; off <<= 1)
#pragma unroll
    for (int mi = 0; mi < 2; ++mi)
#pragma unroll
      for (int r = 0; r < 4; ++r)
        rsum[mi][r] += __shfl_xor(rsum[mi][r], off, 64);
  if (l16 == 0) {
#pragma unroll
    for (int mi = 0; mi < 2; ++mi)
#pragma unroll
      for (int r = 0; r < 4; ++r)
        reds[w][mi * 16 + q4 * 4 + r] = rsum[mi][r];
  }
  __syncthreads();
#pragma unroll
  for (int mi = 0; mi < 2; ++mi)
#pragma unroll
    for (int r = 0; r < 4; ++r) {
      const int row = mi * 16 + q4 * 4 + r;
      const float inv = 1.0f / (reds[0][row] + reds[1][row] + reds[2][row] + reds[3][row]);
#pragma unroll
      for (int ni = 0; ni < 6; ++ni)
        P[row * 392 + w * 96 + ni * 16 + l16] = f2b(accS[mi][ni][r] * inv);
    }
  __syncthreads();

  // ---- O_partial = P_chunk @ V_chunk (per wave), then cross-wave reduce ----
  f32x4 accO[2][4] = {};
#pragma unroll
  for (int ks = 0; ks < 3; ++ks) {
    const int blk = blks[ks];
    bf16x8 ap[2];
#pragma unroll
    for (int mi = 0; mi < 2; ++mi)
      ap[mi] = *(const bf16x8*)&P[(mi * 16 + l16) * 392 + w * 96 + ks * 32 + q4 * 8];
#pragma unroll
    for (int ni = 0; ni < 4; ++ni) {
      bf16x8 bv = *(const bf16x8*)&Vh[(size_t)(ni * 16 + l16) * NSEQ + blk * 32 + q4 * 8];
#pragma unroll
      for (int mi = 0; mi < 2; ++mi)
        accO[mi][ni] = __builtin_amdgcn_mfma_f32_16x16x32_bf16(ap[mi], bv, accO[mi][ni], 0, 0, 0);
    }
  }
#pragma unroll
  for (int mi = 0; mi < 2; ++mi)
#pragma unroll
    for (int ni = 0; ni < 4; ++ni)
#pragma unroll
      for (int r = 0; r < 4; ++r)
        Ored[w][mi * 16 + q4 * 4 + r][ni * 16 + l16] = accO[mi][ni][r];
  __syncthreads();
  for (int e = tid; e < 2048; e += 256) {
    const int r = e >> 6, d = e & 63;
    const float s = Ored[0][r][d] + Ored[1][r][d] + Ored[2][r][d] + Ored[3][r][d];
    Oat[(size_t)(b * NSEQ + t * 32 + r) * E + h * HD + d] = f2b(s);
  }
}

extern "C" void kernel_launch(void* const* d_in, const int* in_sizes, int n_in,
                              void* d_out, int out_size, void* d_ws, size_t ws_size,
                              hipStream_t stream) {
  (void)in_sizes; (void)n_in; (void)out_size; (void)ws_size;
  const void* x  = d_in[0];
  const void* wq = d_in[1];
  const void* wk = d_in[2];
  const void* wv = d_in[3];
  const void* wo = d_in[4];

  // workspace layout (16B-aligned offsets); xc aliases Oat (disjoint lifetimes)
  u16* Wt  = (u16*)d_ws;               // 4 * 1048576 bf16 (W_Q^T, W_K^T, W_V^T, W_O^T)
  u16* Qb  = Wt + 4 * 1048576;         // Q (b,h,n,d) | K (b,h,n,d) | V^T (b,h,d,n)
  u16* Oat = Qb + 3 * 4194304;         // xc (bf16 x) then attention output (b,n,e)
  u16* xc  = Oat;
  float* xp = (float*)(Oat + 4194304); // 131072 f32
  float* Qp = xp + 131072;             // 131072 f32
  float* Kp = Qp + 131072;             // 131072 f32
  float* sc = Kp + 131072;             // 4096 f32
  int* idxs = (int*)(sc + 4096);       // 768 int
  int* flag = idxs + 768;              // 1 int

  detect_k<<<dim3(1), 64, 0, stream>>>((const u16*)x, flag);
  xconv_k<<<dim3(2048), 256, 0, stream>>>(x, xc, flag);
  transpose4<<<dim3(32, 32, 4), 256, 0, stream>>>(wq, wk, wv, wo, Wt, flag);
  xpmean_k<<<dim3(128), 256, 0, stream>>>(x, xp, flag);
  qpkp_k<<<dim3(128, 2), 256, 0, stream>>>(xp, wq, wk, Qp, Kp, flag);
  avgsc_k<<<dim3(64), 64, 0, stream>>>(Qp, Kp, sc);
  topk_k<<<dim3(1), 64, 0, stream>>>(sc, idxs);
  gemm_bt<0><<<dim3(32, 8, 3), 256, 0, stream>>>(xc, Wt, Qb, flag);
  attn_k<<<dim3(64, NH, 2), 256, 0, stream>>>(Qb, Qb + 4194304, Qb + 2 * 4194304, idxs, Oat);
  gemm_bt<1><<<dim3(32, 8, 1), 256, 0, stream>>>(Oat, Wt + 3 * 1048576, d_out, flag);
}

// Round 3
// 237.562 us; speedup vs baseline: 1.2821x; 1.2821x over previous
//
#include <hip/hip_runtime.h>
#include <hip/hip_bf16.h>
#include <stdint.h>

#define E     1024
#define NSEQ  2048
#define NH    16
#define HD    64
#define KSEL  12
#define MROWS 4096   // B*N

typedef unsigned short u16;
typedef __attribute__((ext_vector_type(8))) short bf16x8;
typedef __attribute__((ext_vector_type(4))) float f32x4;
typedef __attribute__((ext_vector_type(4))) unsigned short u16x4;

__device__ __forceinline__ float b2f(u16 u) {
  return __builtin_bit_cast(float, (unsigned)u << 16);
}
__device__ __forceinline__ u16 f2b(float f) {
  return __builtin_bit_cast(u16, __float2bfloat16(f));
}

__device__ __forceinline__ void gload_lds16(const void* g, void* l) {
  auto gp = reinterpret_cast<__attribute__((address_space(1))) unsigned int*>(
      reinterpret_cast<uintptr_t>(g));
  auto lp = reinterpret_cast<__attribute__((address_space(3))) unsigned int*>(
      reinterpret_cast<uintptr_t>(l));
  __builtin_amdgcn_global_load_lds(gp, lp, 16, 0, 0);
}

// ---------------- dtype detector: flag=1 if bf16, 0 if fp32 -------------------
__global__ void detect_k(const u16* __restrict__ x, int* __restrict__ flag) {
  int cnt = 0;
  for (int i = threadIdx.x; i < 1024; i += 64) {
    const unsigned e = (x[i] >> 7) & 0xFF;
    cnt += (e >= 100 && e <= 140) ? 1 : 0;
  }
#pragma unroll
  for (int off = 1; off < 64; off <<= 1) cnt += __shfl_xor(cnt, off, 64);
  if (threadIdx.x == 0) flag[0] = (cnt > 900) ? 1 : 0;
}

// ---------------- x -> bf16 copy (convert if fp32) ----------------------------
__global__ void xconv_k(const void* __restrict__ xin, u16* __restrict__ xc,
                        const int* __restrict__ flag) {
  const int f = flag[0];
  const int stride = gridDim.x * blockDim.x;
  if (f) {
    const u16* s = (const u16*)xin;
    for (int i = blockIdx.x * blockDim.x + threadIdx.x; i < MROWS * E; i += stride)
      xc[i] = s[i];
  } else {
    const float* s = (const float*)xin;
    for (int i = blockIdx.x * blockDim.x + threadIdx.x; i < MROWS * E; i += stride)
      xc[i] = f2b(s[i]);
  }
}

// ---------------- weight transpose: Wt[n][k] = bf16(W[k][n]), 4 weights -------
__global__ void transpose4(const void* __restrict__ w0, const void* __restrict__ w1,
                           const void* __restrict__ w2, const void* __restrict__ w3,
                           u16* __restrict__ Wt, const int* __restrict__ flag) {
  __shared__ u16 tile[32][33];
  const void* W = blockIdx.z == 0 ? w0 : blockIdx.z == 1 ? w1 : blockIdx.z == 2 ? w2 : w3;
  const int f = flag[0];
  u16* O = Wt + (size_t)blockIdx.z * (E * E);
  const int tx = threadIdx.x & 31, ty = threadIdx.x >> 5;
  const int bk = blockIdx.y * 32, bn = blockIdx.x * 32;
  if (f) {
    const u16* Wu = (const u16*)W;
    for (int r = ty; r < 32; r += 8)
      tile[r][tx] = Wu[(size_t)(bk + r) * E + bn + tx];
  } else {
    const float* Wf = (const float*)W;
    for (int r = ty; r < 32; r += 8)
      tile[r][tx] = f2b(Wf[(size_t)(bk + r) * E + bn + tx]);
  }
  __syncthreads();
  for (int r = ty; r < 32; r += 8)
    O[(size_t)(bn + r) * E + bk + tx] = tile[tx][r];
}

// ---------------- xp = per-block mean of x (fp32, original precision) ---------
__global__ void xpmean_k(const void* __restrict__ xin, float* __restrict__ xp,
                         const int* __restrict__ flag) {
  const int blk = blockIdx.x;              // rows blk*32 .. +31
  const int f = flag[0];
  const size_t base = (size_t)blk * 32 * E;
  if (f) {
    const u16* x = (const u16*)xin;
    for (int c = threadIdx.x; c < E; c += 256) {
      float s = 0.f;
      for (int r = 0; r < 32; ++r) s += b2f(x[base + (size_t)r * E + c]);
      xp[(size_t)blk * E + c] = s * (1.0f / 32.0f);
    }
  } else {
    const float* x = (const float*)xin;
    for (int c = threadIdx.x; c < E; c += 256) {
      float s = 0.f;
      for (int r = 0; r < 32; ++r) s += x[base + (size_t)r * E + c];
      xp[(size_t)blk * E + c] = s * (1.0f / 32.0f);
    }
  }
}

// ---------------- P = xp(128xE) @ [Wq|Wk], K-split tiled fp32 GEMM ------------
// grid (16 col-tiles, 2 mats, 16 k-splits); block 256.
// Ppart layout: [mat][ks][128][E] fp32 (16 MB), aliased over Qb region.
__global__ void qpkp2_k(const float* __restrict__ xp, const void* __restrict__ Wq,
                        const void* __restrict__ Wk, float* __restrict__ Ppart,
                        const int* __restrict__ flag) {
  __shared__ float xpT[64][129];   // [kk][row], pad 129: conflict-free both ways
  __shared__ float wS[64][64];     // [kk][col]
  const int c0 = blockIdx.x * 64, k0 = blockIdx.z * 64;
  const int mat = blockIdx.y;
  const int tid = threadIdx.x;
  const int f = flag[0];
  const void* W = mat ? Wk : Wq;
#pragma unroll
  for (int it = 0; it < 32; ++it) {
    const int i = it * 256 + tid;        // 8192 = 128 rows x 64 k
    const int row = i >> 6, kk = i & 63;
    xpT[kk][row] = xp[(size_t)row * E + k0 + kk];
  }
  if (f) {
    const u16* Wu = (const u16*)W;
#pragma unroll
    for (int it = 0; it < 16; ++it) {
      const int i = it * 256 + tid;      // 4096 = 64 k x 64 cols
      const int kk = i >> 6, c = i & 63;
      wS[kk][c] = b2f(Wu[(size_t)(k0 + kk) * E + c0 + c]);
    }
  } else {
    const float* Wf = (const float*)W;
#pragma unroll
    for (int it = 0; it < 16; ++it) {
      const int i = it * 256 + tid;
      const int kk = i >> 6, c = i & 63;
      wS[kk][c] = Wf[(size_t)(k0 + kk) * E + c0 + c];
    }
  }
  __syncthreads();
  const int cq = (tid & 15) * 4;         // 4 cols
  const int r0 = (tid >> 4) * 8;         // 8 contiguous rows
  float acc[8][4] = {};
  for (int kk = 0; kk < 64; ++kk) {
    const f32x4 b = *(const f32x4*)&wS[kk][cq];
    float a[8];
#pragma unroll
    for (int j = 0; j < 8; ++j) a[j] = xpT[kk][r0 + j];
#pragma unroll
    for (int j = 0; j < 8; ++j)
#pragma unroll
      for (int c = 0; c < 4; ++c)
        acc[j][c] += a[j] * b[c];
  }
  float* P = Ppart + (size_t)(mat * 16 + blockIdx.z) * 128 * E;
#pragma unroll
  for (int j = 0; j < 8; ++j)
    *(f32x4*)&P[(size_t)(r0 + j) * E + c0 + cq] = *(const f32x4*)acc[j];
}

// ---------------- reduce 16 k-split partials -> Qp, Kp ------------------------
__global__ void qpred_k(const float* __restrict__ Ppart, float* __restrict__ Qp,
                        float* __restrict__ Kp) {
  const int fidx = blockIdx.x * 256 + threadIdx.x;   // 65536 float4s total
  const int mat = fidx >> 15;
  const int rem = fidx & 32767;
  const float* src = Ppart + (size_t)mat * 16 * 128 * E + (size_t)rem * 4;
  f32x4 s = {};
#pragma unroll
  for (int ks = 0; ks < 16; ++ks)
    s += *(const f32x4*)(src + (size_t)ks * 128 * E);
  float* out = mat ? Kp : Qp;
  *(f32x4*)(out + (size_t)rem * 4) = s;
}

// ---------------- avg_sc[i][j] = (1/32) sum_b Qp[b,i,:].Kp[b,j,:] -------------
__global__ void avgsc_k(const float* __restrict__ Qp, const float* __restrict__ Kp,
                        float* __restrict__ sc) {
  const int i = blockIdx.x;
  const int j = threadIdx.x & 63, s = threadIdx.x >> 6;  // 256 threads
  __shared__ float qrow[2][E];
  __shared__ float red[4][64];
  for (int e = threadIdx.x; e < 2 * E; e += 256)
    qrow[e >> 10][e & 1023] = Qp[(size_t)((e >> 10) * 64 + i) * E + (e & 1023)];
  __syncthreads();
  float acc = 0.f;
  for (int b = 0; b < 2; ++b) {
    const float* kr = Kp + (size_t)(b * 64 + j) * E + s * 256;
    const float* qr = qrow[b] + s * 256;
    for (int e = 0; e < 256; e += 4)
      acc += qr[e] * kr[e] + qr[e + 1] * kr[e + 1] + qr[e + 2] * kr[e + 2] + qr[e + 3] * kr[e + 3];
  }
  red[s][j] = acc;
  __syncthreads();
  if (threadIdx.x < 64)
    sc[i * 64 + threadIdx.x] = (red[0][threadIdx.x] + red[1][threadIdx.x] +
                                red[2][threadIdx.x] + red[3][threadIdx.x]) * (1.0f / 32.0f);
}

// ---------------- top-12 per row of 64x64 score matrix ------------------------
__global__ void topk_k(const float* __restrict__ sc, int* __restrict__ idxs) {
  __shared__ float s[64][65];
  const int tid = threadIdx.x;                 // 64 threads
  for (int e = tid; e < 4096; e += 64) s[e >> 6][e & 63] = sc[e];
  __syncthreads();
  for (int j = 0; j < KSEL; ++j) {
    float m = -3.4e38f;
    int mi = 0;
    for (int c = 0; c < 64; ++c) {
      float v = s[tid][c];
      if (v > m) { m = v; mi = c; }
    }
    idxs[tid * KSEL + j] = mi;
    s[tid][mi] = -3.4e38f;
  }
}

// ---------------- 128x128 bf16 GEMM: C = A(M,K) @ Bt(N,K)^T -------------------
// MODE 0: QKV, blockIdx.z picks weight/output; z=0/1 write (b,h,n,d), z=2 writes (b,h,d,n)
// MODE 1: final projection; output dtype branches on flag (bf16 or fp32)
template <int MODE>
__launch_bounds__(256, 2)
__global__ void gemm_bt(const u16* __restrict__ A, const u16* __restrict__ BtBase,
                        void* __restrict__ OutBase, const int* __restrict__ flag) {
  __shared__ __attribute__((aligned(16))) u16 At[128 * 32];
  __shared__ __attribute__((aligned(16))) u16 Bs[128 * 32];
  const int tid = threadIdx.x;
  const int wave = tid >> 6, lane = tid & 63;
  const int q4 = lane >> 4, l16 = lane & 15;
  const int wm = (wave >> 1) * 64, wn = (wave & 1) * 64;
  const int bm = blockIdx.x * 128, bn = blockIdx.y * 128;
  const u16* Bmat = BtBase + (MODE == 0 ? (size_t)blockIdx.z * (E * E) : 0);
  const int srow = lane >> 2;          // 0..15
  const int scol = (lane & 3) * 8;     // 0,8,16,24

  f32x4 acc[4][4] = {};

  for (int k0 = 0; k0 < E; k0 += 32) {
#pragma unroll
    for (int r = 0; r < 2; ++r) {
      const int c = r * 4 + wave;
      const int row = c * 16 + srow;
      gload_lds16(A + (size_t)(bm + row) * E + k0 + scol, &At[c * 512 + lane * 8]);
      gload_lds16(Bmat + (size_t)(bn + row) * E + k0 + scol, &Bs[c * 512 + lane * 8]);
    }
    __syncthreads();
    bf16x8 af[4], bfr[4];
#pragma unroll
    for (int mi = 0; mi < 4; ++mi)
      af[mi] = *(const bf16x8*)&At[(wm + mi * 16 + l16) * 32 + q4 * 8];
#pragma unroll
    for (int ni = 0; ni < 4; ++ni)
      bfr[ni] = *(const bf16x8*)&Bs[(wn + ni * 16 + l16) * 32 + q4 * 8];
#pragma unroll
    for (int mi = 0; mi < 4; ++mi)
#pragma unroll
      for (int ni = 0; ni < 4; ++ni)
        acc[mi][ni] = __builtin_amdgcn_mfma_f32_16x16x32_bf16(af[mi], bfr[ni], acc[mi][ni], 0, 0, 0);
    __syncthreads();
  }

  if (MODE == 1) {
    const int f = flag[0];
    if (f) {
      u16* Out = (u16*)OutBase;
#pragma unroll
      for (int mi = 0; mi < 4; ++mi) {
        const int rg0 = bm + wm + mi * 16 + q4 * 4;
#pragma unroll
        for (int ni = 0; ni < 4; ++ni) {
          const int cg = bn + wn + ni * 16 + l16;
#pragma unroll
          for (int r = 0; r < 4; ++r)
            Out[(size_t)(rg0 + r) * E + cg] = f2b(acc[mi][ni][r]);
        }
      }
    } else {
      float* Out = (float*)OutBase;
#pragma unroll
      for (int mi = 0; mi < 4; ++mi) {
        const int rg0 = bm + wm + mi * 16 + q4 * 4;
#pragma unroll
        for (int ni = 0; ni < 4; ++ni) {
          const int cg = bn + wn + ni * 16 + l16;
#pragma unroll
          for (int r = 0; r < 4; ++r)
            Out[(size_t)(rg0 + r) * E + cg] = acc[mi][ni][r];
        }
      }
    }
  } else {
    const int z = blockIdx.z;
    u16* O = (u16*)OutBase + (size_t)z * 4194304;
    if (z < 2) {
#pragma unroll
      for (int mi = 0; mi < 4; ++mi) {
        const int rg0 = bm + wm + mi * 16 + q4 * 4;
        const int b = rg0 >> 11, n0 = rg0 & 2047;
#pragma unroll
        for (int ni = 0; ni < 4; ++ni) {
          const int cg = bn + wn + ni * 16 + l16;
          const int h = cg >> 6, d = cg & 63;
          u16* dst = O + (size_t)(b * NH + h) * NSEQ * HD + d;
#pragma unroll
          for (int r = 0; r < 4; ++r)
            dst[(size_t)(n0 + r) * HD] = f2b(acc[mi][ni][r]);
        }
      }
    } else {
#pragma unroll
      for (int mi = 0; mi < 4; ++mi) {
        const int rg0 = bm + wm + mi * 16 + q4 * 4;
        const int b = rg0 >> 11, n0 = rg0 & 2047;
#pragma unroll
        for (int ni = 0; ni < 4; ++ni) {
          const int cg = bn + wn + ni * 16 + l16;
          const int h = cg >> 6, d = cg & 63;
          u16x4 v;
          v.x = f2b(acc[mi][ni][0]);
          v.y = f2b(acc[mi][ni][1]);
          v.z = f2b(acc[mi][ni][2]);
          v.w = f2b(acc[mi][ni][3]);
          *(u16x4*)(O + ((size_t)(b * NH + h) * HD + d) * NSEQ + n0) = v;
        }
      }
    }
  }
}

// ---------------- sparse attention: one block per (t,h,b) ---------------------
// Q,K in (b,h,n,d); V in (b,h,d,n). 4 waves; wave w owns selected blocks 3w..3w+2.
__launch_bounds__(256, 2)
__global__ void attn_k(const u16* __restrict__ Q, const u16* __restrict__ K,
                       const u16* __restrict__ Vt, const int* __restrict__ idxs,
                       u16* __restrict__ Oat) {
  const int t = blockIdx.x, h = blockIdx.y, b = blockIdx.z;
  const int tid = threadIdx.x, w = tid >> 6, lane = tid & 63;
  const int q4 = lane >> 4, l16 = lane & 15;
  __shared__ __attribute__((aligned(16))) u16 P[32 * 392];  // padded stride 392
  __shared__ float Ored[4][32][64];
  __shared__ float redm[4][32];
  __shared__ float reds[4][32];
  const size_t hb = (size_t)(b * NH + h) * NSEQ * HD;
  const u16* Qh = Q + hb;
  const u16* Kh = K + hb;
  const u16* Vh = Vt + hb;   // (d, n) layout, same head stride
  int blks[3];
#pragma unroll
  for (int i = 0; i < 3; ++i) blks[i] = idxs[t * KSEL + w * 3 + i];

  // ---- S = Q K^T for this wave's 96 keys ----
  f32x4 accS[2][6] = {};
#pragma unroll
  for (int ks = 0; ks < 2; ++ks) {
    bf16x8 aq[2];
#pragma unroll
    for (int mi = 0; mi < 2; ++mi)
      aq[mi] = *(const bf16x8*)&Qh[(size_t)(t * 32 + mi * 16 + l16) * HD + ks * 32 + q4 * 8];
#pragma unroll
    for (int ni = 0; ni < 6; ++ni) {
      const int n = blks[ni >> 1] * 32 + (ni & 1) * 16 + l16;
      bf16x8 bk = *(const bf16x8*)&Kh[(size_t)n * HD + ks * 32 + q4 * 8];
#pragma unroll
      for (int mi = 0; mi < 2; ++mi)
        accS[mi][ni] = __builtin_amdgcn_mfma_f32_16x16x32_bf16(aq[mi], bk, accS[mi][ni], 0, 0, 0);
    }
  }

  // ---- softmax (rows spread over 16-lane groups; cross-wave via LDS) ----
  float rmax[2][4];
#pragma unroll
  for (int mi = 0; mi < 2; ++mi)
#pragma unroll
    for (int r = 0; r < 4; ++r) {
      float m = accS[mi][0][r];
#pragma unroll
      for (int ni = 1; ni < 6; ++ni) m = fmaxf(m, accS[mi][ni][r]);
      rmax[mi][r] = m;
    }
#pragma unroll
  for (int off = 1; off < 16; off <<= 1)
#pragma unroll
    for (int mi = 0; mi < 2; ++mi)
#pragma unroll
      for (int r = 0; r < 4; ++r)
        rmax[mi][r] = fmaxf(rmax[mi][r], __shfl_xor(rmax[mi][r], off, 64));
  if (l16 == 0) {
#pragma unroll
    for (int mi = 0; mi < 2; ++mi)
#pragma unroll
      for (int r = 0; r < 4; ++r)
        redm[w][mi * 16 + q4 * 4 + r] = rmax[mi][r];
  }
  __syncthreads();
  const float cexp = 0.125f * 1.44269504088896f;  // scale * log2(e)
  float gmax[2][4];
#pragma unroll
  for (int mi = 0; mi < 2; ++mi)
#pragma unroll
    for (int r = 0; r < 4; ++r) {
      const int row = mi * 16 + q4 * 4 + r;
      gmax[mi][r] = fmaxf(fmaxf(redm[0][row], redm[1][row]), fmaxf(redm[2][row], redm[3][row]));
    }
  float rsum[2][4] = {};
#pragma unroll
  for (int mi = 0; mi < 2; ++mi)
#pragma unroll
    for (int ni = 0; ni < 6; ++ni)
#pragma unroll
      for (int r = 0; r < 4; ++r) {
        const float e = __builtin_exp2f((accS[mi][ni][r] - gmax[mi][r]) * cexp);
        accS[mi][ni][r] = e;
        rsum[mi][r] += e;
      }
#pragma unroll
  for (int off = 1; off < 16; off <<= 1)
#pragma unroll
    for (int mi = 0; mi < 2; ++mi)
#pragma unroll
      for (int r = 0; r < 4; ++r)
        rsum[mi][r] += __shfl_xor(rsum[mi][r], off, 64);
  if (l16 == 0) {
#pragma unroll
    for (int mi = 0; mi < 2; ++mi)
#pragma unroll
      for (int r = 0; r < 4; ++r)
        reds[w][mi * 16 + q4 * 4 + r] = rsum[mi][r];
  }
  __syncthreads();
#pragma unroll
  for (int mi = 0; mi < 2; ++mi)
#pragma unroll
    for (int r = 0; r < 4; ++r) {
      const int row = mi * 16 + q4 * 4 + r;
      const float inv = 1.0f / (reds[0][row] + reds[1][row] + reds[2][row] + reds[3][row]);
#pragma unroll
      for (int ni = 0; ni < 6; ++ni)
        P[row * 392 + w * 96 + ni * 16 + l16] = f2b(accS[mi][ni][r] * inv);
    }
  __syncthreads();

  // ---- O_partial = P_chunk @ V_chunk (per wave), then cross-wave reduce ----
  f32x4 accO[2][4] = {};
#pragma unroll
  for (int ks = 0; ks < 3; ++ks) {
    const int blk = blks[ks];
    bf16x8 ap[2];
#pragma unroll
    for (int mi = 0; mi < 2; ++mi)
      ap[mi] = *(const bf16x8*)&P[(mi * 16 + l16) * 392 + w * 96 + ks * 32 + q4 * 8];
#pragma unroll
    for (int ni = 0; ni < 4; ++ni) {
      bf16x8 bv = *(const bf16x8*)&Vh[(size_t)(ni * 16 + l16) * NSEQ + blk * 32 + q4 * 8];
#pragma unroll
      for (int mi = 0; mi < 2; ++mi)
        accO[mi][ni] = __builtin_amdgcn_mfma_f32_16x16x32_bf16(ap[mi], bv, accO[mi][ni], 0, 0, 0);
    }
  }
#pragma unroll
  for (int mi = 0; mi < 2; ++mi)
#pragma unroll
    for (int ni = 0; ni < 4; ++ni)
#pragma unroll
      for (int r = 0; r < 4; ++r)
        Ored[w][mi * 16 + q4 * 4 + r][ni * 16 + l16] = accO[mi][ni][r];
  __syncthreads();
  for (int e = tid; e < 2048; e += 256) {
    const int r = e >> 6, d = e & 63;
    const float s = Ored[0][r][d] + Ored[1][r][d] + Ored[2][r][d] + Ored[3][r][d];
    Oat[(size_t)(b * NSEQ + t * 32 + r) * E + h * HD + d] = f2b(s);
  }
}

extern "C" void kernel_launch(void* const* d_in, const int* in_sizes, int n_in,
                              void* d_out, int out_size, void* d_ws, size_t ws_size,
                              hipStream_t stream) {
  (void)in_sizes; (void)n_in; (void)out_size; (void)ws_size;
  const void* x  = d_in[0];
  const void* wq = d_in[1];
  const void* wk = d_in[2];
  const void* wv = d_in[3];
  const void* wo = d_in[4];

  // workspace layout (16B-aligned offsets)
  // xc aliases Oat (disjoint lifetimes); Ppart aliases Qb (disjoint lifetimes)
  u16* Wt  = (u16*)d_ws;               // 4 * 1048576 bf16 (W_Q^T, W_K^T, W_V^T, W_O^T)
  u16* Qb  = Wt + 4 * 1048576;         // Q (b,h,n,d) | K (b,h,n,d) | V^T (b,h,d,n)
  u16* Oat = Qb + 3 * 4194304;         // xc (bf16 x) then attention output (b,n,e)
  u16* xc  = Oat;
  float* Ppart = (float*)Qb;           // 16 MB k-split partials (dead before gemm_bt<0>)
  float* xp = (float*)(Oat + 4194304); // 131072 f32
  float* Qp = xp + 131072;             // 131072 f32
  float* Kp = Qp + 131072;             // 131072 f32
  float* sc = Kp + 131072;             // 4096 f32
  int* idxs = (int*)(sc + 4096);       // 768 int
  int* flag = idxs + 768;              // 1 int

  detect_k<<<dim3(1), 64, 0, stream>>>((const u16*)x, flag);
  xconv_k<<<dim3(2048), 256, 0, stream>>>(x, xc, flag);
  transpose4<<<dim3(32, 32, 4), 256, 0, stream>>>(wq, wk, wv, wo, Wt, flag);
  xpmean_k<<<dim3(128), 256, 0, stream>>>(x, xp, flag);
  qpkp2_k<<<dim3(16, 2, 16), 256, 0, stream>>>(xp, wq, wk, Ppart, flag);
  qpred_k<<<dim3(256), 256, 0, stream>>>(Ppart, Qp, Kp);
  avgsc_k<<<dim3(64), 256, 0, stream>>>(Qp, Kp, sc);
  topk_k<<<dim3(1), 64, 0, stream>>>(sc, idxs);
  gemm_bt<0><<<dim3(32, 8, 3), 256, 0, stream>>>(xc, Wt, Qb, flag);
  attn_k<<<dim3(64, NH, 2), 256, 0, stream>>>(Qb, Qb + 4194304, Qb + 2 * 4194304, idxs, Oat);
  gemm_bt<1><<<dim3(32, 8, 1), 256, 0, stream>>>(Oat, Wt + 3 * 1048576, d_out, flag);
}

// Round 4
// 229.811 us; speedup vs baseline: 1.3253x; 1.0337x over previous
//
#include <hip/hip_runtime.h>
#include <hip/hip_bf16.h>
#include <stdint.h>

#define E     1024
#define NSEQ  2048
#define NH    16
#define HD    64
#define KSEL  12
#define MROWS 4096   // B*N

typedef unsigned short u16;
typedef __attribute__((ext_vector_type(8))) short bf16x8;
typedef __attribute__((ext_vector_type(4))) float f32x4;
typedef __attribute__((ext_vector_type(4))) unsigned short u16x4;

__device__ __forceinline__ float b2f(u16 u) {
  return __builtin_bit_cast(float, (unsigned)u << 16);
}
__device__ __forceinline__ u16 f2b(float f) {
  return __builtin_bit_cast(u16, __float2bfloat16(f));
}

__device__ __forceinline__ void gload_lds16(const void* g, void* l) {
  auto gp = reinterpret_cast<__attribute__((address_space(1))) unsigned int*>(
      reinterpret_cast<uintptr_t>(g));
  auto lp = reinterpret_cast<__attribute__((address_space(3))) unsigned int*>(
      reinterpret_cast<uintptr_t>(l));
  __builtin_amdgcn_global_load_lds(gp, lp, 16, 0, 0);
}

// ---------------- dtype detector: flag=1 if bf16, 0 if fp32 -------------------
__global__ void detect_k(const u16* __restrict__ x, int* __restrict__ flag) {
  int cnt = 0;
  for (int i = threadIdx.x; i < 1024; i += 64) {
    const unsigned e = (x[i] >> 7) & 0xFF;
    cnt += (e >= 100 && e <= 140) ? 1 : 0;
  }
#pragma unroll
  for (int off = 1; off < 64; off <<= 1) cnt += __shfl_xor(cnt, off, 64);
  if (threadIdx.x == 0) flag[0] = (cnt > 900) ? 1 : 0;
}

// ---------------- x -> bf16 copy (convert if fp32), vectorized ----------------
__global__ void xconv_k(const void* __restrict__ xin, u16* __restrict__ xc,
                        const int* __restrict__ flag) {
  const int f = flag[0];
  const int stride = gridDim.x * blockDim.x;
  const int n4 = MROWS * E / 4;
  if (f) {
    const u16x4* s = (const u16x4*)xin;
    u16x4* d = (u16x4*)xc;
    for (int i = blockIdx.x * blockDim.x + threadIdx.x; i < n4; i += stride)
      d[i] = s[i];
  } else {
    const f32x4* s = (const f32x4*)xin;
    for (int i = blockIdx.x * blockDim.x + threadIdx.x; i < n4; i += stride) {
      const f32x4 v = s[i];
      u16x4 o;
      o.x = f2b(v.x); o.y = f2b(v.y); o.z = f2b(v.z); o.w = f2b(v.w);
      *(u16x4*)(xc + (size_t)i * 4) = o;
    }
  }
}

// ---------------- weight transpose: Wt[n][k] = bf16(W[k][n]), 4 weights -------
__global__ void transpose4(const void* __restrict__ w0, const void* __restrict__ w1,
                           const void* __restrict__ w2, const void* __restrict__ w3,
                           u16* __restrict__ Wt, const int* __restrict__ flag) {
  __shared__ u16 tile[32][33];
  const void* W = blockIdx.z == 0 ? w0 : blockIdx.z == 1 ? w1 : blockIdx.z == 2 ? w2 : w3;
  const int f = flag[0];
  u16* O = Wt + (size_t)blockIdx.z * (E * E);
  const int tx = threadIdx.x & 31, ty = threadIdx.x >> 5;
  const int bk = blockIdx.y * 32, bn = blockIdx.x * 32;
  if (f) {
    const u16* Wu = (const u16*)W;
    for (int r = ty; r < 32; r += 8)
      tile[r][tx] = Wu[(size_t)(bk + r) * E + bn + tx];
  } else {
    const float* Wf = (const float*)W;
    for (int r = ty; r < 32; r += 8)
      tile[r][tx] = f2b(Wf[(size_t)(bk + r) * E + bn + tx]);
  }
  __syncthreads();
  for (int r = ty; r < 32; r += 8)
    O[(size_t)(bn + r) * E + bk + tx] = tile[tx][r];
}

// ---------------- xp = per-block mean of x (fp32, original precision) ---------
__global__ void xpmean_k(const void* __restrict__ xin, float* __restrict__ xp,
                         const int* __restrict__ flag) {
  const int blk = blockIdx.x;              // rows blk*32 .. +31
  const int f = flag[0];
  const size_t base = (size_t)blk * 32 * E;
  if (f) {
    const u16* x = (const u16*)xin;
    for (int c = threadIdx.x; c < E; c += 256) {
      float s = 0.f;
      for (int r = 0; r < 32; ++r) s += b2f(x[base + (size_t)r * E + c]);
      xp[(size_t)blk * E + c] = s * (1.0f / 32.0f);
    }
  } else {
    const float* x = (const float*)xin;
    for (int c = threadIdx.x; c < E; c += 256) {
      float s = 0.f;
      for (int r = 0; r < 32; ++r) s += x[base + (size_t)r * E + c];
      xp[(size_t)blk * E + c] = s * (1.0f / 32.0f);
    }
  }
}

// ---------------- P = xp(128xE) @ [Wq|Wk], K-split tiled fp32 GEMM ------------
__global__ void qpkp2_k(const float* __restrict__ xp, const void* __restrict__ Wq,
                        const void* __restrict__ Wk, float* __restrict__ Ppart,
                        const int* __restrict__ flag) {
  __shared__ float xpT[64][129];
  __shared__ float wS[64][64];
  const int c0 = blockIdx.x * 64, k0 = blockIdx.z * 64;
  const int mat = blockIdx.y;
  const int tid = threadIdx.x;
  const int f = flag[0];
  const void* W = mat ? Wk : Wq;
#pragma unroll
  for (int it = 0; it < 32; ++it) {
    const int i = it * 256 + tid;
    const int row = i >> 6, kk = i & 63;
    xpT[kk][row] = xp[(size_t)row * E + k0 + kk];
  }
  if (f) {
    const u16* Wu = (const u16*)W;
#pragma unroll
    for (int it = 0; it < 16; ++it) {
      const int i = it * 256 + tid;
      const int kk = i >> 6, c = i & 63;
      wS[kk][c] = b2f(Wu[(size_t)(k0 + kk) * E + c0 + c]);
    }
  } else {
    const float* Wf = (const float*)W;
#pragma unroll
    for (int it = 0; it < 16; ++it) {
      const int i = it * 256 + tid;
      const int kk = i >> 6, c = i & 63;
      wS[kk][c] = Wf[(size_t)(k0 + kk) * E + c0 + c];
    }
  }
  __syncthreads();
  const int cq = (tid & 15) * 4;
  const int r0 = (tid >> 4) * 8;
  float acc[8][4] = {};
  for (int kk = 0; kk < 64; ++kk) {
    const f32x4 b = *(const f32x4*)&wS[kk][cq];
    float a[8];
#pragma unroll
    for (int j = 0; j < 8; ++j) a[j] = xpT[kk][r0 + j];
#pragma unroll
    for (int j = 0; j < 8; ++j)
#pragma unroll
      for (int c = 0; c < 4; ++c)
        acc[j][c] += a[j] * b[c];
  }
  float* P = Ppart + (size_t)(mat * 16 + blockIdx.z) * 128 * E;
#pragma unroll
  for (int j = 0; j < 8; ++j)
    *(f32x4*)&P[(size_t)(r0 + j) * E + c0 + cq] = *(const f32x4*)acc[j];
}

// ---------------- reduce 16 k-split partials -> Qp, Kp ------------------------
__global__ void qpred_k(const float* __restrict__ Ppart, float* __restrict__ Qp,
                        float* __restrict__ Kp) {
  const int fidx = blockIdx.x * 256 + threadIdx.x;
  const int mat = fidx >> 15;
  const int rem = fidx & 32767;
  const float* src = Ppart + (size_t)mat * 16 * 128 * E + (size_t)rem * 4;
  f32x4 s = {};
#pragma unroll
  for (int ks = 0; ks < 16; ++ks)
    s += *(const f32x4*)(src + (size_t)ks * 128 * E);
  float* out = mat ? Kp : Qp;
  *(f32x4*)(out + (size_t)rem * 4) = s;
}

// ---------------- avg_sc[i][j] = (1/32) sum_b Qp[b,i,:].Kp[b,j,:] -------------
__global__ void avgsc_k(const float* __restrict__ Qp, const float* __restrict__ Kp,
                        float* __restrict__ sc) {
  const int i = blockIdx.x;
  const int j = threadIdx.x & 63, s = threadIdx.x >> 6;
  __shared__ float qrow[2][E];
  __shared__ float red[4][64];
  for (int e = threadIdx.x; e < 2 * E; e += 256)
    qrow[e >> 10][e & 1023] = Qp[(size_t)((e >> 10) * 64 + i) * E + (e & 1023)];
  __syncthreads();
  float acc = 0.f;
  for (int b = 0; b < 2; ++b) {
    const float* kr = Kp + (size_t)(b * 64 + j) * E + s * 256;
    const float* qr = qrow[b] + s * 256;
    for (int e = 0; e < 256; e += 4)
      acc += qr[e] * kr[e] + qr[e + 1] * kr[e + 1] + qr[e + 2] * kr[e + 2] + qr[e + 3] * kr[e + 3];
  }
  red[s][j] = acc;
  __syncthreads();
  if (threadIdx.x < 64)
    sc[i * 64 + threadIdx.x] = (red[0][threadIdx.x] + red[1][threadIdx.x] +
                                red[2][threadIdx.x] + red[3][threadIdx.x]) * (1.0f / 32.0f);
}

// ---------------- top-12 per row of 64x64 score matrix ------------------------
__global__ void topk_k(const float* __restrict__ sc, int* __restrict__ idxs) {
  __shared__ float s[64][65];
  const int tid = threadIdx.x;
  for (int e = tid; e < 4096; e += 64) s[e >> 6][e & 63] = sc[e];
  __syncthreads();
  for (int j = 0; j < KSEL; ++j) {
    float m = -3.4e38f;
    int mi = 0;
    for (int c = 0; c < 64; ++c) {
      float v = s[tid][c];
      if (v > m) { m = v; mi = c; }
    }
    idxs[tid * KSEL + j] = mi;
    s[tid][mi] = -3.4e38f;
  }
}

// ---------------- 128x128 bf16 GEMM: C = A(M,K) @ Bt(N,K)^T -------------------
template <int MODE>
__launch_bounds__(256, 2)
__global__ void gemm_bt(const u16* __restrict__ A, const u16* __restrict__ BtBase,
                        void* __restrict__ OutBase, const int* __restrict__ flag) {
  __shared__ __attribute__((aligned(16))) u16 At[128 * 32];
  __shared__ __attribute__((aligned(16))) u16 Bs[128 * 32];
  const int tid = threadIdx.x;
  const int wave = tid >> 6, lane = tid & 63;
  const int q4 = lane >> 4, l16 = lane & 15;
  const int wm = (wave >> 1) * 64, wn = (wave & 1) * 64;
  const int bm = blockIdx.x * 128, bn = blockIdx.y * 128;
  const u16* Bmat = BtBase + (MODE == 0 ? (size_t)blockIdx.z * (E * E) : 0);
  const int srow = lane >> 2;
  const int scol = (lane & 3) * 8;

  f32x4 acc[4][4] = {};

  for (int k0 = 0; k0 < E; k0 += 32) {
#pragma unroll
    for (int r = 0; r < 2; ++r) {
      const int c = r * 4 + wave;
      const int row = c * 16 + srow;
      gload_lds16(A + (size_t)(bm + row) * E + k0 + scol, &At[c * 512 + lane * 8]);
      gload_lds16(Bmat + (size_t)(bn + row) * E + k0 + scol, &Bs[c * 512 + lane * 8]);
    }
    __syncthreads();
    bf16x8 af[4], bfr[4];
#pragma unroll
    for (int mi = 0; mi < 4; ++mi)
      af[mi] = *(const bf16x8*)&At[(wm + mi * 16 + l16) * 32 + q4 * 8];
#pragma unroll
    for (int ni = 0; ni < 4; ++ni)
      bfr[ni] = *(const bf16x8*)&Bs[(wn + ni * 16 + l16) * 32 + q4 * 8];
#pragma unroll
    for (int mi = 0; mi < 4; ++mi)
#pragma unroll
      for (int ni = 0; ni < 4; ++ni)
        acc[mi][ni] = __builtin_amdgcn_mfma_f32_16x16x32_bf16(af[mi], bfr[ni], acc[mi][ni], 0, 0, 0);
    __syncthreads();
  }

  if (MODE == 1) {
    const int f = flag[0];
    if (f) {
      u16* Out = (u16*)OutBase;
#pragma unroll
      for (int mi = 0; mi < 4; ++mi) {
        const int rg0 = bm + wm + mi * 16 + q4 * 4;
#pragma unroll
        for (int ni = 0; ni < 4; ++ni) {
          const int cg = bn + wn + ni * 16 + l16;
#pragma unroll
          for (int r = 0; r < 4; ++r)
            Out[(size_t)(rg0 + r) * E + cg] = f2b(acc[mi][ni][r]);
        }
      }
    } else {
      float* Out = (float*)OutBase;
#pragma unroll
      for (int mi = 0; mi < 4; ++mi) {
        const int rg0 = bm + wm + mi * 16 + q4 * 4;
#pragma unroll
        for (int ni = 0; ni < 4; ++ni) {
          const int cg = bn + wn + ni * 16 + l16;
#pragma unroll
          for (int r = 0; r < 4; ++r)
            Out[(size_t)(rg0 + r) * E + cg] = acc[mi][ni][r];
        }
      }
    }
  } else {
    const int z = blockIdx.z;
    u16* O = (u16*)OutBase + (size_t)z * 4194304;
    if (z < 2) {
#pragma unroll
      for (int mi = 0; mi < 4; ++mi) {
        const int rg0 = bm + wm + mi * 16 + q4 * 4;
        const int b = rg0 >> 11, n0 = rg0 & 2047;
#pragma unroll
        for (int ni = 0; ni < 4; ++ni) {
          const int cg = bn + wn + ni * 16 + l16;
          const int h = cg >> 6, d = cg & 63;
          u16* dst = O + (size_t)(b * NH + h) * NSEQ * HD + d;
#pragma unroll
          for (int r = 0; r < 4; ++r)
            dst[(size_t)(n0 + r) * HD] = f2b(acc[mi][ni][r]);
        }
      }
    } else {
#pragma unroll
      for (int mi = 0; mi < 4; ++mi) {
        const int rg0 = bm + wm + mi * 16 + q4 * 4;
        const int b = rg0 >> 11, n0 = rg0 & 2047;
#pragma unroll
        for (int ni = 0; ni < 4; ++ni) {
          const int cg = bn + wn + ni * 16 + l16;
          const int h = cg >> 6, d = cg & 63;
          u16x4 v;
          v.x = f2b(acc[mi][ni][0]);
          v.y = f2b(acc[mi][ni][1]);
          v.z = f2b(acc[mi][ni][2]);
          v.w = f2b(acc[mi][ni][3]);
          *(u16x4*)(O + ((size_t)(b * NH + h) * HD + d) * NSEQ + n0) = v;
        }
      }
    }
  }
}

// ---------------- sparse attention ------------------------------------------
// 1-D grid 2048, XCD-swizzled: xcd=id&7 -> hb group, so each XCD's L2 holds
// 4 (h,b) pairs' K/V (~1 MB each) across its 64 t-tiles.
// Phase 1 (QK^T+softmax): wave w handles selected blocks 3w..3w+2 (96 keys).
// Phase 2 (PV): wave w handles d-columns 16w..16w+15, sums over ALL 12 blocks.
// This removes the 32 KB cross-wave O-reduction buffer (58.9 -> 26.1 KB LDS).
__launch_bounds__(256, 4)
__global__ void attn_k(const u16* __restrict__ Q, const u16* __restrict__ K,
                       const u16* __restrict__ Vt, const int* __restrict__ idxs,
                       u16* __restrict__ Oat) {
  const int id = blockIdx.x;
  const int xcd = id & 7, g = id >> 3;
  const int t = g & 63;
  const int hb = xcd * 4 + (g >> 6);
  const int h = hb & 15, b = hb >> 4;
  const int tid = threadIdx.x, w = tid >> 6, lane = tid & 63;
  const int q4 = lane >> 4, l16 = lane & 15;
  __shared__ __attribute__((aligned(16))) u16 P[32 * 392];  // padded stride 392
  __shared__ float redm[4][32];
  __shared__ float reds[4][32];
  const size_t hbo = (size_t)(b * NH + h) * NSEQ * HD;
  const u16* Qh = Q + hbo;
  const u16* Kh = K + hbo;
  const u16* Vh = Vt + hbo;   // (d, n) layout
  int blks[3];
#pragma unroll
  for (int i = 0; i < 3; ++i) blks[i] = idxs[t * KSEL + w * 3 + i];

  // ---- S = Q K^T for this wave's 96 keys ----
  f32x4 accS[2][6] = {};
#pragma unroll
  for (int ks = 0; ks < 2; ++ks) {
    bf16x8 aq[2];
#pragma unroll
    for (int mi = 0; mi < 2; ++mi)
      aq[mi] = *(const bf16x8*)&Qh[(size_t)(t * 32 + mi * 16 + l16) * HD + ks * 32 + q4 * 8];
#pragma unroll
    for (int ni = 0; ni < 6; ++ni) {
      const int n = blks[ni >> 1] * 32 + (ni & 1) * 16 + l16;
      bf16x8 bk = *(const bf16x8*)&Kh[(size_t)n * HD + ks * 32 + q4 * 8];
#pragma unroll
      for (int mi = 0; mi < 2; ++mi)
        accS[mi][ni] = __builtin_amdgcn_mfma_f32_16x16x32_bf16(aq[mi], bk, accS[mi][ni], 0, 0, 0);
    }
  }

  // ---- softmax (cross-wave max/sum via tiny LDS) ----
  float rmax[2][4];
#pragma unroll
  for (int mi = 0; mi < 2; ++mi)
#pragma unroll
    for (int r = 0; r < 4; ++r) {
      float m = accS[mi][0][r];
#pragma unroll
      for (int ni = 1; ni < 6; ++ni) m = fmaxf(m, accS[mi][ni][r]);
      rmax[mi][r] = m;
    }
#pragma unroll
  for (int off = 1; off < 16; off <<= 1)
#pragma unroll
    for (int mi = 0; mi < 2; ++mi)
#pragma unroll
      for (int r = 0; r < 4; ++r)
        rmax[mi][r] = fmaxf(rmax[mi][r], __shfl_xor(rmax[mi][r], off, 64));
  if (l16 == 0) {
#pragma unroll
    for (int mi = 0; mi < 2; ++mi)
#pragma unroll
      for (int r = 0; r < 4; ++r)
        redm[w][mi * 16 + q4 * 4 + r] = rmax[mi][r];
  }
  __syncthreads();
  const float cexp = 0.125f * 1.44269504088896f;  // scale * log2(e)
  float gmax[2][4];
#pragma unroll
  for (int mi = 0; mi < 2; ++mi)
#pragma unroll
    for (int r = 0; r < 4; ++r) {
      const int row = mi * 16 + q4 * 4 + r;
      gmax[mi][r] = fmaxf(fmaxf(redm[0][row], redm[1][row]), fmaxf(redm[2][row], redm[3][row]));
    }
  float rsum[2][4] = {};
#pragma unroll
  for (int mi = 0; mi < 2; ++mi)
#pragma unroll
    for (int ni = 0; ni < 6; ++ni)
#pragma unroll
      for (int r = 0; r < 4; ++r) {
        const float e = __builtin_exp2f((accS[mi][ni][r] - gmax[mi][r]) * cexp);
        accS[mi][ni][r] = e;
        rsum[mi][r] += e;
      }
#pragma unroll
  for (int off = 1; off < 16; off <<= 1)
#pragma unroll
    for (int mi = 0; mi < 2; ++mi)
#pragma unroll
      for (int r = 0; r < 4; ++r)
        rsum[mi][r] += __shfl_xor(rsum[mi][r], off, 64);
  if (l16 == 0) {
#pragma unroll
    for (int mi = 0; mi < 2; ++mi)
#pragma unroll
      for (int r = 0; r < 4; ++r)
        reds[w][mi * 16 + q4 * 4 + r] = rsum[mi][r];
  }
  __syncthreads();
  // normalized P -> LDS; column chunk q=3w+(ni>>1) holds keys of block idxs[t*12+q]
#pragma unroll
  for (int mi = 0; mi < 2; ++mi)
#pragma unroll
    for (int r = 0; r < 4; ++r) {
      const int row = mi * 16 + q4 * 4 + r;
      const float inv = 1.0f / (reds[0][row] + reds[1][row] + reds[2][row] + reds[3][row]);
#pragma unroll
      for (int ni = 0; ni < 6; ++ni)
        P[row * 392 + w * 96 + ni * 16 + l16] = f2b(accS[mi][ni][r] * inv);
    }
  __syncthreads();

  // ---- O[:, 16w..16w+15] = P @ V  (each wave: all 12 blocks, own d-slice) ----
  f32x4 accO[2] = {};
#pragma unroll
  for (int q = 0; q < KSEL; ++q) {
    const int blk = idxs[t * KSEL + q];
    const bf16x8 bv = *(const bf16x8*)&Vh[(size_t)(w * 16 + l16) * NSEQ + blk * 32 + q4 * 8];
#pragma unroll
    for (int mi = 0; mi < 2; ++mi) {
      const bf16x8 ap = *(const bf16x8*)&P[(mi * 16 + l16) * 392 + q * 32 + q4 * 8];
      accO[mi] = __builtin_amdgcn_mfma_f32_16x16x32_bf16(ap, bv, accO[mi], 0, 0, 0);
    }
  }
#pragma unroll
  for (int mi = 0; mi < 2; ++mi) {
    const int row0 = t * 32 + mi * 16 + q4 * 4;
#pragma unroll
    for (int r = 0; r < 4; ++r)
      Oat[(size_t)(b * NSEQ + row0 + r) * E + h * HD + w * 16 + l16] = f2b(accO[mi][r]);
  }
}

extern "C" void kernel_launch(void* const* d_in, const int* in_sizes, int n_in,
                              void* d_out, int out_size, void* d_ws, size_t ws_size,
                              hipStream_t stream) {
  (void)in_sizes; (void)n_in; (void)out_size; (void)ws_size;
  const void* x  = d_in[0];
  const void* wq = d_in[1];
  const void* wk = d_in[2];
  const void* wv = d_in[3];
  const void* wo = d_in[4];

  u16* Wt  = (u16*)d_ws;               // 4 * 1048576 bf16 (W_Q^T, W_K^T, W_V^T, W_O^T)
  u16* Qb  = Wt + 4 * 1048576;         // Q (b,h,n,d) | K (b,h,n,d) | V^T (b,h,d,n)
  u16* Oat = Qb + 3 * 4194304;         // xc (bf16 x) then attention output (b,n,e)
  u16* xc  = Oat;
  float* Ppart = (float*)Qb;           // 16 MB k-split partials (dead before gemm_bt<0>)
  float* xp = (float*)(Oat + 4194304); // 131072 f32
  float* Qp = xp + 131072;             // 131072 f32
  float* Kp = Qp + 131072;             // 131072 f32
  float* sc = Kp + 131072;             // 4096 f32
  int* idxs = (int*)(sc + 4096);       // 768 int
  int* flag = idxs + 768;              // 1 int

  detect_k<<<dim3(1), 64, 0, stream>>>((const u16*)x, flag);
  xconv_k<<<dim3(1024), 256, 0, stream>>>(x, xc, flag);
  transpose4<<<dim3(32, 32, 4), 256, 0, stream>>>(wq, wk, wv, wo, Wt, flag);
  xpmean_k<<<dim3(128), 256, 0, stream>>>(x, xp, flag);
  qpkp2_k<<<dim3(16, 2, 16), 256, 0, stream>>>(xp, wq, wk, Ppart, flag);
  qpred_k<<<dim3(256), 256, 0, stream>>>(Ppart, Qp, Kp);
  avgsc_k<<<dim3(64), 256, 0, stream>>>(Qp, Kp, sc);
  topk_k<<<dim3(1), 64, 0, stream>>>(sc, idxs);
  gemm_bt<0><<<dim3(32, 8, 3), 256, 0, stream>>>(xc, Wt, Qb, flag);
  attn_k<<<dim3(2048), 256, 0, stream>>>(Qb, Qb + 4194304, Qb + 2 * 4194304, idxs, Oat);
  gemm_bt<1><<<dim3(32, 8, 1), 256, 0, stream>>>(Oat, Wt + 3 * 1048576, d_out, flag);
}

// Round 5
// 206.793 us; speedup vs baseline: 1.4728x; 1.1113x over previous
//
#include <hip/hip_runtime.h>
#include <hip/hip_bf16.h>
#include <stdint.h>

#define E     1024
#define NSEQ  2048
#define NH    16
#define HD    64
#define KSEL  12
#define MROWS 4096   // B*N

typedef unsigned short u16;
typedef __attribute__((ext_vector_type(8))) short bf16x8;
typedef __attribute__((ext_vector_type(4))) float f32x4;
typedef __attribute__((ext_vector_type(4))) unsigned short u16x4;

__device__ __forceinline__ float b2f(u16 u) {
  return __builtin_bit_cast(float, (unsigned)u << 16);
}
__device__ __forceinline__ u16 f2b(float f) {
  return __builtin_bit_cast(u16, __float2bfloat16(f));
}

__device__ __forceinline__ void gload_lds16(const void* g, void* l) {
  auto gp = reinterpret_cast<__attribute__((address_space(1))) unsigned int*>(
      reinterpret_cast<uintptr_t>(g));
  auto lp = reinterpret_cast<__attribute__((address_space(3))) unsigned int*>(
      reinterpret_cast<uintptr_t>(l));
  __builtin_amdgcn_global_load_lds(gp, lp, 16, 0, 0);
}

// ============ prep: xconv (1024 blk) + W-transpose (1024 blk) + xpmean (128) ==
// Every block computes the dtype flag locally (wave 0, 2KB read); block 0
// publishes it for downstream kernels. flag=1 bf16, 0 fp32.
__global__ void prep_k(const void* __restrict__ xin,
                       const void* __restrict__ w0, const void* __restrict__ w1,
                       const void* __restrict__ w2, const void* __restrict__ w3,
                       u16* __restrict__ xc, u16* __restrict__ Wt,
                       float* __restrict__ xp, int* __restrict__ flagOut) {
  __shared__ u16 tile[64][66];   // pad 66: 33-dword row stride -> 2-way (free)
  __shared__ int flagL;
  const int id = blockIdx.x, tid = threadIdx.x;
  if (tid < 64) {
    const u16* xu = (const u16*)xin;
    int cnt = 0;
    for (int i = tid; i < 1024; i += 64) {
      const unsigned e = (xu[i] >> 7) & 0xFF;
      cnt += (e >= 100 && e <= 140) ? 1 : 0;
    }
#pragma unroll
    for (int off = 1; off < 64; off <<= 1) cnt += __shfl_xor(cnt, off, 64);
    if (tid == 0) flagL = (cnt > 900) ? 1 : 0;
  }
  __syncthreads();
  const int f = flagL;
  if (id == 0 && tid == 0) flagOut[0] = f;

  if (id < 1024) {
    // ---- x -> bf16 copy ----
    const int n4 = MROWS * E / 4;
    if (f) {
      const u16x4* s = (const u16x4*)xin;
      u16x4* d = (u16x4*)xc;
      for (int i = id * 256 + tid; i < n4; i += 1024 * 256) d[i] = s[i];
    } else {
      const f32x4* s = (const f32x4*)xin;
      for (int i = id * 256 + tid; i < n4; i += 1024 * 256) {
        const f32x4 v = s[i];
        u16x4 o;
        o.x = f2b(v.x); o.y = f2b(v.y); o.z = f2b(v.z); o.w = f2b(v.w);
        *(u16x4*)(xc + (size_t)i * 4) = o;
      }
    }
  } else if (id < 2048) {
    // ---- Wt[n][k] = bf16(W[k][n]), 64x64 tile per block ----
    const int tt = id - 1024;
    const int mat = tt >> 8, q = tt & 255;
    const int bn = (q & 15) * 64, bk = (q >> 4) * 64;
    const void* W = mat == 0 ? w0 : mat == 1 ? w1 : mat == 2 ? w2 : w3;
    u16* O = Wt + (size_t)mat * (E * E);
    const int tx = tid & 63, ty = tid >> 6;
    if (f) {
      const u16* Wu = (const u16*)W;
#pragma unroll
      for (int i = 0; i < 16; ++i) {
        const int r = ty + 4 * i;
        tile[r][tx] = Wu[(size_t)(bk + r) * E + bn + tx];
      }
    } else {
      const float* Wf = (const float*)W;
#pragma unroll
      for (int i = 0; i < 16; ++i) {
        const int r = ty + 4 * i;
        tile[r][tx] = f2b(Wf[(size_t)(bk + r) * E + bn + tx]);
      }
    }
    __syncthreads();
#pragma unroll
    for (int i = 0; i < 16; ++i) {
      const int rr = ty + 4 * i;
      O[(size_t)(bn + rr) * E + bk + tx] = tile[tx][rr];
    }
  } else {
    // ---- xp = per-32-row mean of x (original precision) ----
    const int blk = id - 2048;
    const size_t base = (size_t)blk * 32 * E;
    if (f) {
      const u16* x = (const u16*)xin;
      for (int c = tid; c < E; c += 256) {
        float s = 0.f;
        for (int r = 0; r < 32; ++r) s += b2f(x[base + (size_t)r * E + c]);
        xp[(size_t)blk * E + c] = s * (1.0f / 32.0f);
      }
    } else {
      const float* x = (const float*)xin;
      for (int c = tid; c < E; c += 256) {
        float s = 0.f;
        for (int r = 0; r < 32; ++r) s += x[base + (size_t)r * E + c];
        xp[(size_t)blk * E + c] = s * (1.0f / 32.0f);
      }
    }
  }
}

// ---------------- P = xp(128xE) @ [Wq|Wk], K-split tiled fp32 GEMM ------------
__global__ void qpkp2_k(const float* __restrict__ xp, const void* __restrict__ Wq,
                        const void* __restrict__ Wk, float* __restrict__ Ppart,
                        const int* __restrict__ flag) {
  __shared__ float xpT[64][129];
  __shared__ float wS[64][64];
  const int c0 = blockIdx.x * 64, k0 = blockIdx.z * 64;
  const int mat = blockIdx.y;
  const int tid = threadIdx.x;
  const int f = flag[0];
  const void* W = mat ? Wk : Wq;
#pragma unroll
  for (int it = 0; it < 32; ++it) {
    const int i = it * 256 + tid;
    const int row = i >> 6, kk = i & 63;
    xpT[kk][row] = xp[(size_t)row * E + k0 + kk];
  }
  if (f) {
    const u16* Wu = (const u16*)W;
#pragma unroll
    for (int it = 0; it < 16; ++it) {
      const int i = it * 256 + tid;
      const int kk = i >> 6, c = i & 63;
      wS[kk][c] = b2f(Wu[(size_t)(k0 + kk) * E + c0 + c]);
    }
  } else {
    const float* Wf = (const float*)W;
#pragma unroll
    for (int it = 0; it < 16; ++it) {
      const int i = it * 256 + tid;
      const int kk = i >> 6, c = i & 63;
      wS[kk][c] = Wf[(size_t)(k0 + kk) * E + c0 + c];
    }
  }
  __syncthreads();
  const int cq = (tid & 15) * 4;
  const int r0 = (tid >> 4) * 8;
  float acc[8][4] = {};
  for (int kk = 0; kk < 64; ++kk) {
    const f32x4 b = *(const f32x4*)&wS[kk][cq];
    float a[8];
#pragma unroll
    for (int j = 0; j < 8; ++j) a[j] = xpT[kk][r0 + j];
#pragma unroll
    for (int j = 0; j < 8; ++j)
#pragma unroll
      for (int c = 0; c < 4; ++c)
        acc[j][c] += a[j] * b[c];
  }
  float* P = Ppart + (size_t)(mat * 16 + blockIdx.z) * 128 * E;
#pragma unroll
  for (int j = 0; j < 8; ++j)
    *(f32x4*)&P[(size_t)(r0 + j) * E + c0 + cq] = *(const f32x4*)acc[j];
}

// ---------------- reduce 16 k-split partials -> Qp, Kp ------------------------
__global__ void qpred_k(const float* __restrict__ Ppart, float* __restrict__ Qp,
                        float* __restrict__ Kp) {
  const int fidx = blockIdx.x * 256 + threadIdx.x;
  const int mat = fidx >> 15;
  const int rem = fidx & 32767;
  const float* src = Ppart + (size_t)mat * 16 * 128 * E + (size_t)rem * 4;
  f32x4 s = {};
#pragma unroll
  for (int ks = 0; ks < 16; ++ks)
    s += *(const f32x4*)(src + (size_t)ks * 128 * E);
  float* out = mat ? Kp : Qp;
  *(f32x4*)(out + (size_t)rem * 4) = s;
}

// ---------------- shared GEMM core: 128x128 bf16 tile, C = A @ Bt^T -----------
__device__ __forceinline__ void gemm_core(const u16* __restrict__ A,
                                          const u16* __restrict__ Bt,
                                          int bm, int bnG, int wave, int lane,
                                          u16* At, u16* Bs, f32x4 (&acc)[4][4]) {
  const int srow = lane >> 2, scol = (lane & 3) * 8;
  const int q4 = lane >> 4, l16 = lane & 15;
  const int wm = (wave >> 1) * 64, wn = (wave & 1) * 64;
  for (int k0 = 0; k0 < E; k0 += 32) {
#pragma unroll
    for (int r = 0; r < 2; ++r) {
      const int c = r * 4 + wave;
      const int row = c * 16 + srow;
      gload_lds16(A + (size_t)(bm + row) * E + k0 + scol, &At[c * 512 + lane * 8]);
      gload_lds16(Bt + (size_t)(bnG + row) * E + k0 + scol, &Bs[c * 512 + lane * 8]);
    }
    __syncthreads();
    bf16x8 af[4], bfr[4];
#pragma unroll
    for (int mi = 0; mi < 4; ++mi)
      af[mi] = *(const bf16x8*)&At[(wm + mi * 16 + l16) * 32 + q4 * 8];
#pragma unroll
    for (int ni = 0; ni < 4; ++ni)
      bfr[ni] = *(const bf16x8*)&Bs[(wn + ni * 16 + l16) * 32 + q4 * 8];
#pragma unroll
    for (int mi = 0; mi < 4; ++mi)
#pragma unroll
      for (int ni = 0; ni < 4; ++ni)
        acc[mi][ni] = __builtin_amdgcn_mfma_f32_16x16x32_bf16(af[mi], bfr[ni], acc[mi][ni], 0, 0, 0);
    __syncthreads();
  }
}

// ============ gemmsel: QKV projection (768 blk) + avgsc (64 blk) ==============
// id<768: gemm block, bm=(id&31)*128, global n-tile by=id>>5 over [Wq|Wk|Wv]^T.
// id>=768: avg_sc row block i=id-768.
__launch_bounds__(256, 2)
__global__ void gemmsel_k(const u16* __restrict__ A, const u16* __restrict__ WtAll,
                          u16* __restrict__ Qb, const float* __restrict__ Qp,
                          const float* __restrict__ Kp, float* __restrict__ sc) {
  __shared__ __attribute__((aligned(16))) u16 At[128 * 32];
  __shared__ __attribute__((aligned(16))) u16 Bs[128 * 32];
  __shared__ float qrow[2][E];
  __shared__ float red[4][64];
  const int id = blockIdx.x;
  const int tid = threadIdx.x;
  if (id < 768) {
    const int wave = tid >> 6, lane = tid & 63;
    const int q4 = lane >> 4, l16 = lane & 15;
    const int wm = (wave >> 1) * 64, wn = (wave & 1) * 64;
    const int bm = (id & 31) * 128;
    const int by = id >> 5;              // 0..23 over N=3072
    f32x4 acc[4][4] = {};
    gemm_core(A, WtAll, bm, by * 128, wave, lane, At, Bs, acc);
    const int z = by >> 3;               // 0=Q 1=K 2=V
    const int bnw = (by & 7) * 128;
    u16* O = Qb + (size_t)z * 4194304;
    if (z < 2) {
#pragma unroll
      for (int mi = 0; mi < 4; ++mi) {
        const int rg0 = bm + wm + mi * 16 + q4 * 4;
        const int b = rg0 >> 11, n0 = rg0 & 2047;
#pragma unroll
        for (int ni = 0; ni < 4; ++ni) {
          const int cg = bnw + wn + ni * 16 + l16;
          const int h = cg >> 6, d = cg & 63;
          u16* dst = O + (size_t)(b * NH + h) * NSEQ * HD + d;
#pragma unroll
          for (int r = 0; r < 4; ++r)
            dst[(size_t)(n0 + r) * HD] = f2b(acc[mi][ni][r]);
        }
      }
    } else {
#pragma unroll
      for (int mi = 0; mi < 4; ++mi) {
        const int rg0 = bm + wm + mi * 16 + q4 * 4;
        const int b = rg0 >> 11, n0 = rg0 & 2047;
#pragma unroll
        for (int ni = 0; ni < 4; ++ni) {
          const int cg = bnw + wn + ni * 16 + l16;
          const int h = cg >> 6, d = cg & 63;
          u16x4 v;
          v.x = f2b(acc[mi][ni][0]);
          v.y = f2b(acc[mi][ni][1]);
          v.z = f2b(acc[mi][ni][2]);
          v.w = f2b(acc[mi][ni][3]);
          *(u16x4*)(O + ((size_t)(b * NH + h) * HD + d) * NSEQ + n0) = v;
        }
      }
    }
  } else {
    // ---- avg_sc[i][j] = (1/32) sum_b Qp[b,i,:].Kp[b,j,:] ----
    const int i = id - 768;
    const int j = tid & 63, s = tid >> 6;
    for (int e = tid; e < 2 * E; e += 256)
      qrow[e >> 10][e & 1023] = Qp[(size_t)((e >> 10) * 64 + i) * E + (e & 1023)];
    __syncthreads();
    float acc = 0.f;
    for (int b = 0; b < 2; ++b) {
      const float* kr = Kp + (size_t)(b * 64 + j) * E + s * 256;
      const float* qr = qrow[b] + s * 256;
      for (int e = 0; e < 256; e += 4)
        acc += qr[e] * kr[e] + qr[e + 1] * kr[e + 1] + qr[e + 2] * kr[e + 2] + qr[e + 3] * kr[e + 3];
    }
    red[s][j] = acc;
    __syncthreads();
    if (tid < 64)
      sc[i * 64 + tid] = (red[0][tid] + red[1][tid] + red[2][tid] + red[3][tid]) * (1.0f / 32.0f);
  }
}

// ---------------- sparse attention (top-12 computed in-block) -----------------
// 1-D grid 2048, XCD-swizzled. Q,K in (b,h,n,d); V in (b,h,d,n).
// Phase 1 (QK^T+softmax): wave w handles selected blocks 3w..3w+2 (96 keys).
// Phase 2 (PV): wave w handles d-columns 16w..16w+15, sums over ALL 12 blocks.
__launch_bounds__(256, 4)
__global__ void attn_k(const u16* __restrict__ Q, const u16* __restrict__ K,
                       const u16* __restrict__ Vt, const float* __restrict__ sc,
                       u16* __restrict__ Oat) {
  const int id = blockIdx.x;
  const int xcd = id & 7, g = id >> 3;
  const int t = g & 63;
  const int hb = xcd * 4 + (g >> 6);
  const int h = hb & 15, b = hb >> 4;
  const int tid = threadIdx.x, w = tid >> 6, lane = tid & 63;
  const int q4 = lane >> 4, l16 = lane & 15;
  __shared__ __attribute__((aligned(16))) u16 P[32 * 392];  // padded stride 392
  __shared__ float redm[4][32];
  __shared__ float reds[4][32];
  __shared__ int selL[KSEL];
  const size_t hbo = (size_t)(b * NH + h) * NSEQ * HD;
  const u16* Qh = Q + hbo;
  const u16* Kh = K + hbo;
  const u16* Vh = Vt + hbo;   // (d, n) layout

  // ---- top-12 of sc row t (wave 0; 12 rounds of packed shfl-argmax) ----
  if (w == 0) {
    float v = sc[t * 64 + lane];
#pragma unroll
    for (int j = 0; j < KSEL; ++j) {
      const unsigned bits = __float_as_uint(v);
      const unsigned mono = (bits & 0x80000000u) ? ~bits : (bits | 0x80000000u);
      unsigned long long key = ((unsigned long long)mono << 6) | (unsigned)(63 - lane);
#pragma unroll
      for (int off = 1; off < 64; off <<= 1) {
        const unsigned long long o = __shfl_xor(key, off, 64);
        if (o > key) key = o;
      }
      const int s = 63 - (int)(key & 63ull);
      if (lane == 0) selL[j] = s;
      if (lane == s) v = -3.4e38f;
    }
  }
  __syncthreads();
  int blks[3];
#pragma unroll
  for (int i = 0; i < 3; ++i) blks[i] = selL[w * 3 + i];

  // ---- S = Q K^T for this wave's 96 keys ----
  f32x4 accS[2][6] = {};
#pragma unroll
  for (int ks = 0; ks < 2; ++ks) {
    bf16x8 aq[2];
#pragma unroll
    for (int mi = 0; mi < 2; ++mi)
      aq[mi] = *(const bf16x8*)&Qh[(size_t)(t * 32 + mi * 16 + l16) * HD + ks * 32 + q4 * 8];
#pragma unroll
    for (int ni = 0; ni < 6; ++ni) {
      const int n = blks[ni >> 1] * 32 + (ni & 1) * 16 + l16;
      bf16x8 bk = *(const bf16x8*)&Kh[(size_t)n * HD + ks * 32 + q4 * 8];
#pragma unroll
      for (int mi = 0; mi < 2; ++mi)
        accS[mi][ni] = __builtin_amdgcn_mfma_f32_16x16x32_bf16(aq[mi], bk, accS[mi][ni], 0, 0, 0);
    }
  }

  // ---- softmax (cross-wave max/sum via tiny LDS) ----
  float rmax[2][4];
#pragma unroll
  for (int mi = 0; mi < 2; ++mi)
#pragma unroll
    for (int r = 0; r < 4; ++r) {
      float m = accS[mi][0][r];
#pragma unroll
      for (int ni = 1; ni < 6; ++ni) m = fmaxf(m, accS[mi][ni][r]);
      rmax[mi][r] = m;
    }
#pragma unroll
  for (int off = 1; off < 16; off <<= 1)
#pragma unroll
    for (int mi = 0; mi < 2; ++mi)
#pragma unroll
      for (int r = 0; r < 4; ++r)
        rmax[mi][r] = fmaxf(rmax[mi][r], __shfl_xor(rmax[mi][r], off, 64));
  if (l16 == 0) {
#pragma unroll
    for (int mi = 0; mi < 2; ++mi)
#pragma unroll
      for (int r = 0; r < 4; ++r)
        redm[w][mi * 16 + q4 * 4 + r] = rmax[mi][r];
  }
  __syncthreads();
  const float cexp = 0.125f * 1.44269504088896f;  // scale * log2(e)
  float gmax[2][4];
#pragma unroll
  for (int mi = 0; mi < 2; ++mi)
#pragma unroll
    for (int r = 0; r < 4; ++r) {
      const int row = mi * 16 + q4 * 4 + r;
      gmax[mi][r] = fmaxf(fmaxf(redm[0][row], redm[1][row]), fmaxf(redm[2][row], redm[3][row]));
    }
  float rsum[2][4] = {};
#pragma unroll
  for (int mi = 0; mi < 2; ++mi)
#pragma unroll
    for (int ni = 0; ni < 6; ++ni)
#pragma unroll
      for (int r = 0; r < 4; ++r) {
        const float e = __builtin_exp2f((accS[mi][ni][r] - gmax[mi][r]) * cexp);
        accS[mi][ni][r] = e;
        rsum[mi][r] += e;
      }
#pragma unroll
  for (int off = 1; off < 16; off <<= 1)
#pragma unroll
    for (int mi = 0; mi < 2; ++mi)
#pragma unroll
      for (int r = 0; r < 4; ++r)
        rsum[mi][r] += __shfl_xor(rsum[mi][r], off, 64);
  if (l16 == 0) {
#pragma unroll
    for (int mi = 0; mi < 2; ++mi)
#pragma unroll
      for (int r = 0; r < 4; ++r)
        reds[w][mi * 16 + q4 * 4 + r] = rsum[mi][r];
  }
  __syncthreads();
  // normalized P -> LDS; column chunk q=3w+(ni>>1) holds keys of block selL[q]
#pragma unroll
  for (int mi = 0; mi < 2; ++mi)
#pragma unroll
    for (int r = 0; r < 4; ++r) {
      const int row = mi * 16 + q4 * 4 + r;
      const float inv = 1.0f / (reds[0][row] + reds[1][row] + reds[2][row] + reds[3][row]);
#pragma unroll
      for (int ni = 0; ni < 6; ++ni)
        P[row * 392 + w * 96 + ni * 16 + l16] = f2b(accS[mi][ni][r] * inv);
    }
  __syncthreads();

  // ---- O[:, 16w..16w+15] = P @ V  (each wave: all 12 blocks, own d-slice) ----
  f32x4 accO[2] = {};
#pragma unroll
  for (int q = 0; q < KSEL; ++q) {
    const int blk = selL[q];
    const bf16x8 bv = *(const bf16x8*)&Vh[(size_t)(w * 16 + l16) * NSEQ + blk * 32 + q4 * 8];
#pragma unroll
    for (int mi = 0; mi < 2; ++mi) {
      const bf16x8 ap = *(const bf16x8*)&P[(mi * 16 + l16) * 392 + q * 32 + q4 * 8];
      accO[mi] = __builtin_amdgcn_mfma_f32_16x16x32_bf16(ap, bv, accO[mi], 0, 0, 0);
    }
  }
#pragma unroll
  for (int mi = 0; mi < 2; ++mi) {
    const int row0 = t * 32 + mi * 16 + q4 * 4;
#pragma unroll
    for (int r = 0; r < 4; ++r)
      Oat[(size_t)(b * NSEQ + row0 + r) * E + h * HD + w * 16 + l16] = f2b(accO[mi][r]);
  }
}

// ---------------- final projection: out = Oat @ Wo^T --------------------------
__launch_bounds__(256, 2)
__global__ void gemmo_k(const u16* __restrict__ A, const u16* __restrict__ Wot,
                        void* __restrict__ OutBase, const int* __restrict__ flag) {
  __shared__ __attribute__((aligned(16))) u16 At[128 * 32];
  __shared__ __attribute__((aligned(16))) u16 Bs[128 * 32];
  const int tid = threadIdx.x;
  const int wave = tid >> 6, lane = tid & 63;
  const int q4 = lane >> 4, l16 = lane & 15;
  const int wm = (wave >> 1) * 64, wn = (wave & 1) * 64;
  const int bm = blockIdx.x * 128, bn = blockIdx.y * 128;
  f32x4 acc[4][4] = {};
  gemm_core(A, Wot, bm, bn, wave, lane, At, Bs, acc);
  const int f = flag[0];
  if (f) {
    u16* Out = (u16*)OutBase;
#pragma unroll
    for (int mi = 0; mi < 4; ++mi) {
      const int rg0 = bm + wm + mi * 16 + q4 * 4;
#pragma unroll
      for (int ni = 0; ni < 4; ++ni) {
        const int cg = bn + wn + ni * 16 + l16;
#pragma unroll
        for (int r = 0; r < 4; ++r)
          Out[(size_t)(rg0 + r) * E + cg] = f2b(acc[mi][ni][r]);
      }
    }
  } else {
    float* Out = (float*)OutBase;
#pragma unroll
    for (int mi = 0; mi < 4; ++mi) {
      const int rg0 = bm + wm + mi * 16 + q4 * 4;
#pragma unroll
      for (int ni = 0; ni < 4; ++ni) {
        const int cg = bn + wn + ni * 16 + l16;
#pragma unroll
        for (int r = 0; r < 4; ++r)
          Out[(size_t)(rg0 + r) * E + cg] = acc[mi][ni][r];
      }
    }
  }
}

extern "C" void kernel_launch(void* const* d_in, const int* in_sizes, int n_in,
                              void* d_out, int out_size, void* d_ws, size_t ws_size,
                              hipStream_t stream) {
  (void)in_sizes; (void)n_in; (void)out_size; (void)ws_size;
  const void* x  = d_in[0];
  const void* wq = d_in[1];
  const void* wk = d_in[2];
  const void* wv = d_in[3];
  const void* wo = d_in[4];

  u16* Wt  = (u16*)d_ws;               // 4 * 1048576 bf16 (W_Q^T, W_K^T, W_V^T, W_O^T)
  u16* Qb  = Wt + 4 * 1048576;         // Q (b,h,n,d) | K (b,h,n,d) | V^T (b,h,d,n)
  u16* Oat = Qb + 3 * 4194304;         // xc (bf16 x) then attention output (b,n,e)
  u16* xc  = Oat;
  float* Ppart = (float*)Qb;           // 16 MB k-split partials (dead before gemmsel)
  float* xp = (float*)(Oat + 4194304); // 131072 f32
  float* Qp = xp + 131072;             // 131072 f32
  float* Kp = Qp + 131072;             // 131072 f32
  float* sc = Kp + 131072;             // 4096 f32
  int* flag = (int*)(sc + 4096) + 768; // 1 int

  prep_k<<<dim3(2176), 256, 0, stream>>>(x, wq, wk, wv, wo, xc, Wt, xp, flag);
  qpkp2_k<<<dim3(16, 2, 16), 256, 0, stream>>>(xp, wq, wk, Ppart, flag);
  qpred_k<<<dim3(256), 256, 0, stream>>>(Ppart, Qp, Kp);
  gemmsel_k<<<dim3(832), 256, 0, stream>>>(xc, Wt, Qb, Qp, Kp, sc);
  attn_k<<<dim3(2048), 256, 0, stream>>>(Qb, Qb + 4194304, Qb + 2 * 4194304, sc, Oat);
  gemmo_k<<<dim3(32, 8), 256, 0, stream>>>(Oat, Wt + 3 * 1048576, d_out, flag);
}